// Round 1
// baseline (494.472 us; speedup 1.0000x reference)
//
#include <hip/hip_runtime.h>

typedef __bf16 bf16;
typedef __bf16 bf16x4 __attribute__((ext_vector_type(4)));
typedef __bf16 bf16x8 __attribute__((ext_vector_type(8)));
typedef float  f32x4  __attribute__((ext_vector_type(4)));

#define B_ 2048
#define T_ 128
#define C_ 256
#define H_ 64

// LDS layout (bytes):
//  phase1: xs[128][72] @0 (18432), Ws[3][64][72] @18432 (27648)  -> 46080
//  phase2: Qs[128][72] @0, Ks[128][72] @18432, Vt[64][136] @36864 (17408) -> 54272
//  phase3: Ps[128][136] @0 (34816, aliases Qs+Ks), Vt kept @36864
// 54272 B * 3 blocks = 162816 <= 163840 (160 KiB/CU) -> 3 blocks/CU
#define SMEM_BYTES 54272

// Pre-kernel: transpose+convert weights to bf16: Wt[slot][h][c], slot 0=Wq,1=Wk,2=Wv
__global__ void wt_kernel(const float* __restrict__ Wk, const float* __restrict__ Wq,
                          const float* __restrict__ Wv, bf16* __restrict__ Wt) {
    int o = blockIdx.x * 256 + threadIdx.x;     // 0..49151
    int slot = o >> 14;
    int h    = (o & 16383) >> 8;
    int cc   = o & 255;
    const float* src = (slot == 0) ? Wq : (slot == 1 ? Wk : Wv);
    Wt[o] = (bf16)src[cc * 64 + h];
}

__global__ void __launch_bounds__(256, 3)
attn_kernel(const float* __restrict__ xg, const bf16* __restrict__ Wt,
            float* __restrict__ outg) {
    __shared__ __align__(16) char smem_raw[SMEM_BYTES];
    bf16* xs  = (bf16*)smem_raw;                 // [128][72]
    bf16* Wsm = (bf16*)(smem_raw + 18432);       // [3][64][72]
    bf16* Qs  = (bf16*)smem_raw;                 // [128][72]
    bf16* Ks  = (bf16*)(smem_raw + 18432);       // [128][72]
    bf16* Vt  = (bf16*)(smem_raw + 36864);       // [64][136]
    bf16* Ps  = (bf16*)smem_raw;                 // [128][136]

    const int tid  = threadIdx.x;
    const int b    = blockIdx.x;
    const int w    = tid >> 6;      // wave 0..3
    const int lane = tid & 63;
    const int quad = lane >> 4;
    const int n16  = lane & 15;

    const f32x4 zero4 = {0.f, 0.f, 0.f, 0.f};

    // ---------------- projections: QKV = x @ [Wq|Wk|Wv] ----------------
    f32x4 acc[2][12];
    #pragma unroll
    for (int mt = 0; mt < 2; mt++)
        #pragma unroll
        for (int nt = 0; nt < 12; nt++) acc[mt][nt] = zero4;

    const float*  xb  = xg + (size_t)b * (T_ * C_);
    const ushort* WtU = (const ushort*)Wt;

    for (int c = 0; c < 4; c++) {               // K chunks of 64
        __syncthreads();                        // prev chunk's LDS reads done
        // stage x chunk: 128x64 fp32 -> bf16 (2048 float4, 8/thread)
        #pragma unroll
        for (int i = 0; i < 8; i++) {
            int f  = tid + 256 * i;
            int t  = f >> 4;
            int c4 = (f & 15) * 4;
            float4 v = *(const float4*)(xb + t * C_ + c * 64 + c4);
            bf16x4 bv = {(bf16)v.x, (bf16)v.y, (bf16)v.z, (bf16)v.w};
            *(bf16x4*)(xs + t * 72 + c4) = bv;
        }
        // stage W chunk: 3x64x64 bf16 (3072 ushort4, 12/thread)
        #pragma unroll
        for (int i = 0; i < 12; i++) {
            int g    = tid + 256 * i;
            int slot = g >> 10;
            int rem  = g & 1023;
            int h    = rem >> 4;
            int c4   = (rem & 15) * 4;
            ushort4 wv = *(const ushort4*)(WtU + slot * 16384 + h * 256 + c * 64 + c4);
            *(ushort4*)((ushort*)Wsm + (slot * 64 + h) * 72 + c4) = wv;
        }
        __syncthreads();
        // MFMA: wave w owns row-tiles {2w, 2w+1}, all 12 col-tiles
        bf16x8 a[2][2];
        #pragma unroll
        for (int mt = 0; mt < 2; mt++)
            #pragma unroll
            for (int ks = 0; ks < 2; ks++)
                a[mt][ks] = *(const bf16x8*)(xs + (16 * (2 * w + mt) + n16) * 72 + 32 * ks + 8 * quad);
        #pragma unroll
        for (int nt = 0; nt < 12; nt++) {
            int row = ((nt >> 2) * 64 + 16 * (nt & 3) + n16) * 72 + 8 * quad;
            bf16x8 b0 = *(const bf16x8*)(Wsm + row);
            bf16x8 b1 = *(const bf16x8*)(Wsm + row + 32);
            #pragma unroll
            for (int mt = 0; mt < 2; mt++) {
                acc[mt][nt] = __builtin_amdgcn_mfma_f32_16x16x32_bf16(a[mt][0], b0, acc[mt][nt], 0, 0, 0);
                acc[mt][nt] = __builtin_amdgcn_mfma_f32_16x16x32_bf16(a[mt][1], b1, acc[mt][nt], 0, 0, 0);
            }
        }
    }
    __syncthreads();                            // all proj MFMAs done; xs/Ws dead

    // write Q[t][h], K[s][h], Vt[h][t] as bf16 (C-layout: row=4*quad+r, col=n16)
    #pragma unroll
    for (int mt = 0; mt < 2; mt++) {
        int tbase = 16 * (2 * w + mt) + 4 * quad;
        #pragma unroll
        for (int nt = 0; nt < 8; nt++) {
            bf16* dst = (nt < 4) ? Qs : Ks;
            int h = 16 * (nt & 3) + n16;
            #pragma unroll
            for (int r = 0; r < 4; r++)
                dst[(tbase + r) * 72 + h] = (bf16)acc[mt][nt][r];
        }
        #pragma unroll
        for (int nt = 8; nt < 12; nt++) {       // V transposed: Vt[h][t]
            int h = 16 * (nt - 8) + n16;
            bf16x4 pv = {(bf16)acc[mt][nt][0], (bf16)acc[mt][nt][1],
                         (bf16)acc[mt][nt][2], (bf16)acc[mt][nt][3]};
            *(bf16x4*)(Vt + h * 136 + tbase) = pv;
        }
    }
    __syncthreads();

    // ---------------- S = Q K^T, causal softmax ----------------
    // causal balance: wave w handles row-tiles {w, 7-w}; sT = s-tiles rounded to even
    f32x4 sacc[2][8];
    int mts[2] = {w, 7 - w};
    #pragma unroll
    for (int half = 0; half < 2; half++) {
        int mt = mts[half];
        int sT = ((mt >> 1) + 1) * 2;
        bf16x8 qa[2];
        #pragma unroll
        for (int ks = 0; ks < 2; ks++)
            qa[ks] = *(const bf16x8*)(Qs + (16 * mt + n16) * 72 + 32 * ks + 8 * quad);
        #pragma unroll
        for (int nt = 0; nt < 8; nt++) {
            sacc[half][nt] = zero4;
            if (nt < sT) {
                bf16x8 kb0 = *(const bf16x8*)(Ks + (16 * nt + n16) * 72 + 8 * quad);
                bf16x8 kb1 = *(const bf16x8*)(Ks + (16 * nt + n16) * 72 + 32 + 8 * quad);
                sacc[half][nt] = __builtin_amdgcn_mfma_f32_16x16x32_bf16(qa[0], kb0, sacc[half][nt], 0, 0, 0);
                sacc[half][nt] = __builtin_amdgcn_mfma_f32_16x16x32_bf16(qa[1], kb1, sacc[half][nt], 0, 0, 0);
            }
        }
        // row softmax: row t lives across one 16-lane quad-group for fixed (r)
        #pragma unroll
        for (int r = 0; r < 4; r++) {
            int t = 16 * mt + 4 * quad + r;
            float mx = -3.0e38f;
            #pragma unroll
            for (int nt = 0; nt < 8; nt++) {
                if (nt < sT) {
                    float v = sacc[half][nt][r] * 0.0625f;      // scale = C^-0.5 = 1/16
                    v = (16 * nt + n16 <= t) ? v : -3.0e38f;     // causal mask
                    sacc[half][nt][r] = v;
                    mx = fmaxf(mx, v);
                }
            }
            mx = fmaxf(mx, __shfl_xor(mx, 1));
            mx = fmaxf(mx, __shfl_xor(mx, 2));
            mx = fmaxf(mx, __shfl_xor(mx, 4));
            mx = fmaxf(mx, __shfl_xor(mx, 8));
            float sum = 0.f;
            #pragma unroll
            for (int nt = 0; nt < 8; nt++) {
                if (nt < sT) {
                    // masked: (-3e38 - mx)*log2e overflows to -inf, exp2 -> 0
                    float p = __builtin_amdgcn_exp2f((sacc[half][nt][r] - mx) * 1.4426950408889634f);
                    sacc[half][nt][r] = p;
                    sum += p;
                }
            }
            sum += __shfl_xor(sum, 1);
            sum += __shfl_xor(sum, 2);
            sum += __shfl_xor(sum, 4);
            sum += __shfl_xor(sum, 8);
            float rinv = 1.0f / sum;
            #pragma unroll
            for (int nt = 0; nt < 8; nt++)
                if (nt < sT) sacc[half][nt][r] *= rinv;
        }
    }
    __syncthreads();                            // all Q/K reads done; Ps may alias

    // write P (bf16) in row-major [t][s] for A-operand reads
    #pragma unroll
    for (int half = 0; half < 2; half++) {
        int mt = mts[half];
        int sT = ((mt >> 1) + 1) * 2;
        #pragma unroll
        for (int nt = 0; nt < 8; nt++) {
            if (nt < sT) {
                #pragma unroll
                for (int r = 0; r < 4; r++)
                    Ps[(16 * mt + 4 * quad + r) * 136 + 16 * nt + n16] = (bf16)sacc[half][nt][r];
            }
        }
    }
    __syncthreads();

    // ---------------- O = P V, store fp32 ----------------
    #pragma unroll
    for (int half = 0; half < 2; half++) {
        int mt  = mts[half];
        int kst = (mt >> 1) + 1;                // k-steps of 32 (covers s-tiles < sT)
        f32x4 oacc[4];
        #pragma unroll
        for (int nt = 0; nt < 4; nt++) oacc[nt] = zero4;
        #pragma unroll
        for (int ks = 0; ks < 4; ks++) {
            if (ks < kst) {
                bf16x8 pa = *(const bf16x8*)(Ps + (16 * mt + n16) * 136 + 32 * ks + 8 * quad);
                #pragma unroll
                for (int nt = 0; nt < 4; nt++) {
                    bf16x8 vb = *(const bf16x8*)(Vt + (16 * nt + n16) * 136 + 32 * ks + 8 * quad);
                    oacc[nt] = __builtin_amdgcn_mfma_f32_16x16x32_bf16(pa, vb, oacc[nt], 0, 0, 0);
                }
            }
        }
        float* ob = outg + ((size_t)b * T_ + 16 * mt + 4 * quad) * H_;
        #pragma unroll
        for (int nt = 0; nt < 4; nt++)
            #pragma unroll
            for (int r = 0; r < 4; r++)
                ob[r * H_ + 16 * nt + n16] = oacc[nt][r];
    }
}

extern "C" void kernel_launch(void* const* d_in, const int* in_sizes, int n_in,
                              void* d_out, int out_size, void* d_ws, size_t ws_size,
                              hipStream_t stream) {
    const float* x  = (const float*)d_in[0];
    const float* Wk = (const float*)d_in[1];
    const float* Wq = (const float*)d_in[2];
    const float* Wv = (const float*)d_in[3];
    bf16* Wt = (bf16*)d_ws;                     // 3*64*256*2 = 98304 B scratch
    wt_kernel<<<192, 256, 0, stream>>>(Wk, Wq, Wv, Wt);
    attn_kernel<<<B_, 256, 0, stream>>>(x, Wt, (float*)d_out);
}